// Round 4
// baseline (6624.056 us; speedup 1.0000x reference)
//
#include <hip/hip_runtime.h>
#include <stdint.h>

typedef __bf16 bf16x8 __attribute__((ext_vector_type(8)));
typedef float floatx4 __attribute__((ext_vector_type(4)));
typedef unsigned int u32x4 __attribute__((ext_vector_type(4)));

#define T_STEPS 512
#define BATCH   64
#define HDIM    512
#define NGATE   1024   // 2*H
#define IDIM    512
#define RBLOCKS 32     // recurrent blocks, 16 cols each

__device__ __forceinline__ unsigned short f2bf(float f) {
  unsigned int u = __builtin_bit_cast(unsigned int, f);
  u += 0x7fffu + ((u >> 16) & 1u);
  return (unsigned short)(u >> 16);
}
__device__ __forceinline__ float bf2f(unsigned short s) {
  unsigned int u = ((unsigned int)s) << 16;
  return __builtin_bit_cast(float, u);
}

// ---------------- fp32 -> bf16 hi + lo residual ----------------
__global__ void cvt_split_kernel(const float4* __restrict__ src,
                                 ushort4* __restrict__ hi, ushort4* __restrict__ lo, int n4) {
  int i = blockIdx.x * blockDim.x + threadIdx.x;
  if (i >= n4) return;
  float4 v = src[i];
  ushort4 h, l;
  h.x = f2bf(v.x); l.x = f2bf(v.x - bf2f(h.x));
  h.y = f2bf(v.y); l.y = f2bf(v.y - bf2f(h.y));
  h.z = f2bf(v.z); l.z = f2bf(v.z - bf2f(h.z));
  h.w = f2bf(v.w); l.w = f2bf(v.w - bf2f(h.w));
  hi[i] = h; lo[i] = l;
}

// biasc[i] = bih[i] + (i < H ? bhh[i] : 0)
__global__ void bias_kernel(const float* __restrict__ a, const float* __restrict__ b,
                            float* __restrict__ c, int n) {
  int i = blockIdx.x * blockDim.x + threadIdx.x;
  if (i < n) c[i] = a[i] + (i < HDIM ? b[i] : 0.0f);
}

// ---------------- async global->LDS 16B ----------------
__device__ __forceinline__ void g2l16(const void* g, void* l) {
  __builtin_amdgcn_global_load_lds(
      (const __attribute__((address_space(1))) unsigned int*)g,
      (__attribute__((address_space(3))) unsigned int*)l, 16, 0, 0);
}

// ---------------- Gi GEMM, split-split: C = (Ahi+Alo)(Bhi+Blo)^T + bias ----------------
__global__ __launch_bounds__(256) void gemm_bt(
    const unsigned short* __restrict__ Ahi,
    const unsigned short* __restrict__ Alo,
    const unsigned short* __restrict__ Bhi,
    const unsigned short* __restrict__ Blo,
    const float* __restrict__ bias,
    float* __restrict__ C,
    int M, int N, int K) {
  __shared__ unsigned short Ahs[128 * 32];
  __shared__ unsigned short Als[128 * 32];
  __shared__ unsigned short Bhs[128 * 32];
  __shared__ unsigned short Bls[128 * 32];
  const int tid  = threadIdx.x;
  const int w    = tid >> 6, lane = tid & 63;
  const int m16  = lane & 15, quad = lane >> 4;
  const int gn   = N >> 7;
  const int by   = blockIdx.x / gn, bx = blockIdx.x % gn;
  const int wm   = w & 1, wn = w >> 1;

  const int rr = lane >> 2;
  const int cc = lane & 3;
  const size_t ro0 = (size_t)((w*2+0)*16 + rr) * K + cc*8;
  const size_t ro1 = (size_t)((w*2+1)*16 + rr) * K + cc*8;
  const unsigned short* Ah0 = Ahi + (size_t)by*128*K + ro0;
  const unsigned short* Ah1 = Ahi + (size_t)by*128*K + ro1;
  const unsigned short* Al0 = Alo + (size_t)by*128*K + ro0;
  const unsigned short* Al1 = Alo + (size_t)by*128*K + ro1;
  const unsigned short* Bh0 = Bhi + (size_t)bx*128*K + ro0;
  const unsigned short* Bh1 = Bhi + (size_t)bx*128*K + ro1;
  const unsigned short* Bl0 = Blo + (size_t)bx*128*K + ro0;
  const unsigned short* Bl1 = Blo + (size_t)bx*128*K + ro1;

  floatx4 acc[4][4] = {};

  for (int k0 = 0; k0 < K; k0 += 32) {
    g2l16(Ah0 + k0, &Ahs[(w*2+0)*512]);
    g2l16(Ah1 + k0, &Ahs[(w*2+1)*512]);
    g2l16(Al0 + k0, &Als[(w*2+0)*512]);
    g2l16(Al1 + k0, &Als[(w*2+1)*512]);
    g2l16(Bh0 + k0, &Bhs[(w*2+0)*512]);
    g2l16(Bh1 + k0, &Bhs[(w*2+1)*512]);
    g2l16(Bl0 + k0, &Bls[(w*2+0)*512]);
    g2l16(Bl1 + k0, &Bls[(w*2+1)*512]);
    __syncthreads();

    bf16x8 ah[4], al[4], bh[4], bl[4];
#pragma unroll
    for (int mt = 0; mt < 4; ++mt) {
      ah[mt] = *(const bf16x8*)&Ahs[(wm*64 + mt*16 + m16)*32 + quad*8];
      al[mt] = *(const bf16x8*)&Als[(wm*64 + mt*16 + m16)*32 + quad*8];
    }
#pragma unroll
    for (int nt = 0; nt < 4; ++nt) {
      bh[nt] = *(const bf16x8*)&Bhs[(wn*64 + nt*16 + m16)*32 + quad*8];
      bl[nt] = *(const bf16x8*)&Bls[(wn*64 + nt*16 + m16)*32 + quad*8];
    }
#pragma unroll
    for (int mt = 0; mt < 4; ++mt)
#pragma unroll
      for (int nt = 0; nt < 4; ++nt) {
        acc[mt][nt] = __builtin_amdgcn_mfma_f32_16x16x32_bf16(ah[mt], bh[nt], acc[mt][nt], 0, 0, 0);
        acc[mt][nt] = __builtin_amdgcn_mfma_f32_16x16x32_bf16(al[mt], bh[nt], acc[mt][nt], 0, 0, 0);
        acc[mt][nt] = __builtin_amdgcn_mfma_f32_16x16x32_bf16(ah[mt], bl[nt], acc[mt][nt], 0, 0, 0);
      }
    __syncthreads();
  }

#pragma unroll
  for (int nt = 0; nt < 4; ++nt) {
    int col = bx*128 + wn*64 + nt*16 + m16;
    float bv = bias[col];
#pragma unroll
    for (int mt = 0; mt < 4; ++mt) {
      int row0 = by*128 + wm*64 + mt*16 + quad*4;
#pragma unroll
      for (int r = 0; r < 4; ++r)
        C[(size_t)(row0 + r)*N + col] = acc[mt][nt][r] + bv;
    }
  }
}

// ---------------- persistent recurrent kernel: wave-cohort HINT flags + phase-verified data ----
// h element = u32: (bf16_hi << 16) | (bf16_lo & ~3) | (t & 3). Double buffer by t&1.
// The flag is a HINT (stored with NO vmcnt drain — removes one fabric RTT from the
// producer critical path). Validity is proven per-element by the 2-bit phase stamp:
// slot for h_{t-1} (parity (t-1)&1) can only hold phase (t-1)&3 (fresh) or
// (t-3)&3 = (t+1)&3 (stale, differs by 2 mod 4) -> detectable. Consumer: poll the
// 4B hint (cheap spin), load payload ONCE, verify phases in-register; rare
// stragglers re-sweep with s_sleep backoff + spin cap (cap -> wrong results, not hang).
// Overwrite safety (skew<=1): producer enters step t+1 only after cohort flags >= t+1;
// a wave publishes flag t+1 only after computing h_t, which data-depends on its fully
// phase-verified h_{t-1} loads. So no producer overwrites h_{t-1} while a reader needs it.
__global__ __launch_bounds__(256, 1) void mgu_recur(
    const float* __restrict__ Gi,            // [T*B, 1024] fp32 (f: both biases; n: b_ih only)
    const unsigned short* __restrict__ Whi,  // [1024, 512] bf16 hi
    const unsigned short* __restrict__ Wlo,  // [1024, 512] bf16 lo
    const float* __restrict__ bhh,           // [1024] fp32 (n-half used)
    unsigned int* __restrict__ hbuf,         // [2][64][512] u32 packed (memset 0x03 = phase 3)
    unsigned int* __restrict__ flags,        // 128 words, stride 32 (zeroed)
    float* __restrict__ out) {               // [T*B, 512] fp32
  const int tid  = threadIdx.x;
  const int w    = tid >> 6, lane = tid & 63;
  const int m16  = lane & 15, quad = lane >> 4;
  const int j0   = blockIdx.x * 16;

  const float bnb = bhh[512 + j0 + m16];   // b_hh_n for this lane's output column

  // W_hh fragments in registers: B[n=lane&15][k=quad*8+j]
  bf16x8 wfh[16], wnh[16], wfl[16], wnl[16];
#pragma unroll
  for (int kk = 0; kk < 16; ++kk) {
    size_t of = (size_t)(j0 + m16)       * 512 + kk*32 + quad*8;
    size_t on = (size_t)(512 + j0 + m16) * 512 + kk*32 + quad*8;
    wfh[kk] = *(const bf16x8*)&Whi[of];
    wnh[kk] = *(const bf16x8*)&Whi[on];
    wfl[kk] = *(const bf16x8*)&Wlo[of];
    wnl[kk] = *(const bf16x8*)&Wlo[on];
  }

  const int arow = w*16 + m16;   // batch row this lane reads for the A fragment

  unsigned int* myflag = flags + (blockIdx.x*4 + w) * 32;
  const unsigned int* pollflag = flags + ((lane & 31)*4 + w) * 32;  // cohort w, block lane&31

#pragma unroll 1
  for (int t = 0; t < T_STEPS; ++t) {
    // Gi prefetch (fp32, h-independent) — overlaps the flag poll
    float gif[4], gin[4];
#pragma unroll
    for (int r = 0; r < 4; ++r) {
      size_t row = (size_t)t*64 + w*16 + quad*4 + r;
      gif[r] = Gi[row*1024 + j0 + m16];
      gin[r] = Gi[row*1024 + 512 + j0 + m16];
    }

    floatx4 accf0 = {}, accf1 = {}, accf2 = {};
    floatx4 accn0 = {}, accn1 = {}, accn2 = {};

    if (t > 0) {
      // cohort HINT poll: 1 word/lane, tight
      unsigned int fv;
      do {
        fv = __hip_atomic_load(pollflag, __ATOMIC_RELAXED, __HIP_MEMORY_SCOPE_AGENT);
      } while (__any((int)(fv < (unsigned int)t)));

      const unsigned int ph = (unsigned int)((t-1) & 3);
      const unsigned long long* hrow =
          (const unsigned long long*)(hbuf + (size_t)((t-1)&1)*BATCH*HDIM)
          + (size_t)arow*256 + quad*4;   // row stride 256 u64; col base quad*8 elems

      unsigned long long pk[16][4];
#pragma unroll
      for (int kk = 0; kk < 16; ++kk)
#pragma unroll
        for (int i = 0; i < 4; ++i)
          pk[kk][i] = __hip_atomic_load(hrow + kk*16 + i,
                        __ATOMIC_RELAXED, __HIP_MEMORY_SCOPE_AGENT);

      // phase verify; rare straggler re-sweep with backoff + cap
      for (int spin = 0; spin < (1 << 16); ++spin) {
        unsigned int badacc = 0u;
#pragma unroll
        for (int kk = 0; kk < 16; ++kk)
#pragma unroll
          for (int i = 0; i < 4; ++i) {
            unsigned int lo32 = (unsigned int)pk[kk][i];
            unsigned int hi32 = (unsigned int)(pk[kk][i] >> 32);
            badacc |= ((lo32 ^ ph) | (hi32 ^ ph)) & 3u;
          }
        if (!__any((int)badacc)) break;
        __builtin_amdgcn_s_sleep(2);
#pragma unroll
        for (int kk = 0; kk < 16; ++kk)
#pragma unroll
          for (int i = 0; i < 4; ++i)
            pk[kk][i] = __hip_atomic_load(hrow + kk*16 + i,
                          __ATOMIC_RELAXED, __HIP_MEMORY_SCOPE_AGENT);
      }

      // unpack (v_perm: 2 per element-pair; mask phase bits out of lo) + MFMA
#pragma unroll
      for (int kk = 0; kk < 16; ++kk) {
        unsigned int e0 = (unsigned int)pk[kk][0], e1 = (unsigned int)(pk[kk][0] >> 32);
        unsigned int e2 = (unsigned int)pk[kk][1], e3 = (unsigned int)(pk[kk][1] >> 32);
        unsigned int e4 = (unsigned int)pk[kk][2], e5 = (unsigned int)(pk[kk][2] >> 32);
        unsigned int e6 = (unsigned int)pk[kk][3], e7 = (unsigned int)(pk[kk][3] >> 32);
        u32x4 h4 = { __builtin_amdgcn_perm(e1, e0, 0x07060302u),
                     __builtin_amdgcn_perm(e3, e2, 0x07060302u),
                     __builtin_amdgcn_perm(e5, e4, 0x07060302u),
                     __builtin_amdgcn_perm(e7, e6, 0x07060302u) };
        u32x4 l4 = { __builtin_amdgcn_perm(e1, e0, 0x05040100u) & 0xFFFCFFFCu,
                     __builtin_amdgcn_perm(e3, e2, 0x05040100u) & 0xFFFCFFFCu,
                     __builtin_amdgcn_perm(e5, e4, 0x05040100u) & 0xFFFCFFFCu,
                     __builtin_amdgcn_perm(e7, e6, 0x05040100u) & 0xFFFCFFFCu };
        bf16x8 ah = __builtin_bit_cast(bf16x8, h4);
        bf16x8 al = __builtin_bit_cast(bf16x8, l4);
        accf0 = __builtin_amdgcn_mfma_f32_16x16x32_bf16(ah, wfh[kk], accf0, 0, 0, 0);
        accf1 = __builtin_amdgcn_mfma_f32_16x16x32_bf16(al, wfh[kk], accf1, 0, 0, 0);
        accf2 = __builtin_amdgcn_mfma_f32_16x16x32_bf16(ah, wfl[kk], accf2, 0, 0, 0);
        accn0 = __builtin_amdgcn_mfma_f32_16x16x32_bf16(ah, wnh[kk], accn0, 0, 0, 0);
        accn1 = __builtin_amdgcn_mfma_f32_16x16x32_bf16(al, wnh[kk], accn1, 0, 0, 0);
        accn2 = __builtin_amdgcn_mfma_f32_16x16x32_bf16(ah, wnl[kk], accn2, 0, 0, 0);
      }
    }

    // gates + nonlinearity (fp32); phase-stamped h stores, then HINT flag (no drain)
    const unsigned int phw = (unsigned int)(t & 3);
    unsigned int* hcur = hbuf + (size_t)(t&1)*BATCH*HDIM;
    float hv[4];
#pragma unroll
    for (int r = 0; r < 4; ++r) {
      float xf = gif[r] + (accf0[r] + accf1[r] + accf2[r]);
      float f  = 1.0f / (1.0f + __expf(-xf));
      float xn = gin[r] + f * (accn0[r] + accn1[r] + accn2[r] + bnb);
      float ex = __expf(-2.0f * xn);
      float h  = (1.0f - ex) / (1.0f + ex);    // tanh
      hv[r] = h;
      unsigned short hh = f2bf(h);
      unsigned short hl = f2bf(h - bf2f(hh));
      unsigned int packed = ((unsigned int)hh << 16) | ((unsigned int)hl & 0xFFFCu) | phw;
      int row = w*16 + quad*4 + r;
      __hip_atomic_store(hcur + (size_t)row*512 + j0 + m16, packed,
                         __ATOMIC_RELAXED, __HIP_MEMORY_SCOPE_AGENT);
    }

    // HINT flag: issued immediately after the h stores, NO vmcnt drain.
    if (lane == 0)
      __hip_atomic_store(myflag, (unsigned int)(t + 1),
                         __ATOMIC_RELAXED, __HIP_MEMORY_SCOPE_AGENT);

    // out store AFTER flag: off the inter-wave critical path
#pragma unroll
    for (int r = 0; r < 4; ++r) {
      int row = w*16 + quad*4 + r;
      __builtin_nontemporal_store(hv[r], &out[((size_t)t*64 + row)*512 + j0 + m16]);
    }
  }
}

// ---------------- launch ----------------
extern "C" void kernel_launch(void* const* d_in, const int* in_sizes, int n_in,
                              void* d_out, int out_size, void* d_ws, size_t ws_size,
                              hipStream_t stream) {
  (void)in_sizes; (void)n_in; (void)out_size; (void)ws_size;
  const float* X   = (const float*)d_in[0];   // [512,64,512]
  const float* Wih = (const float*)d_in[1];   // [1024,512]
  const float* Whh = (const float*)d_in[2];   // [1024,512]
  const float* bih = (const float*)d_in[3];   // [1024]
  const float* bhh = (const float*)d_in[4];   // [1024]
  float* out = (float*)d_out;

  const int TB = T_STEPS * BATCH;  // 32768

  // workspace layout (~207 MB)
  unsigned short* Xhi    = (unsigned short*)d_ws;                    // TB*IDIM bf16
  unsigned short* Xlo    = Xhi   + (size_t)TB * IDIM;
  unsigned short* WihHi  = Xlo   + (size_t)TB * IDIM;                // NGATE*IDIM
  unsigned short* WihLo  = WihHi + (size_t)NGATE * IDIM;
  unsigned short* WhhHi  = WihLo + (size_t)NGATE * IDIM;             // NGATE*HDIM
  unsigned short* WhhLo  = WhhHi + (size_t)NGATE * HDIM;
  float*          biasc  = (float*)(WhhLo + (size_t)NGATE * HDIM);   // NGATE
  float*          Gi     = biasc + NGATE;                            // TB*NGATE fp32
  unsigned int*   hbuf   = (unsigned int*)(Gi + (size_t)TB * NGATE); // [2][64][512] u32
  unsigned int*   flags  = hbuf + (size_t)2 * BATCH * HDIM;          // 128 x stride-32 u32

  // hbuf -> phase 3 (0x03030303): never a valid expected phase (t=1 expects 0, t=2 expects 1)
  (void)hipMemsetAsync(hbuf, 0x03, (size_t)2 * BATCH * HDIM * sizeof(unsigned int), stream);
  (void)hipMemsetAsync(flags, 0, (size_t)RBLOCKS * 4 * 32 * sizeof(unsigned int), stream);

  int n4;
  n4 = TB * IDIM / 4;
  cvt_split_kernel<<<n4/256, 256, 0, stream>>>((const float4*)X, (ushort4*)Xhi, (ushort4*)Xlo, n4);
  n4 = NGATE * IDIM / 4;
  cvt_split_kernel<<<n4/256, 256, 0, stream>>>((const float4*)Wih, (ushort4*)WihHi, (ushort4*)WihLo, n4);
  n4 = NGATE * HDIM / 4;
  cvt_split_kernel<<<n4/256, 256, 0, stream>>>((const float4*)Whh, (ushort4*)WhhHi, (ushort4*)WhhLo, n4);
  bias_kernel<<<4, 256, 0, stream>>>(bih, bhh, biasc, NGATE);

  gemm_bt<<<(TB/128)*(NGATE/128), 256, 0, stream>>>(Xhi, Xlo, WihHi, WihLo, biasc, Gi, TB, NGATE, IDIM);

  mgu_recur<<<RBLOCKS, 256, 0, stream>>>(Gi, WhhHi, WhhLo, bhh, hbuf, flags, out);
}

// Round 8
// 4847.028 us; speedup vs baseline: 1.3666x; 1.3666x over previous
//
#include <hip/hip_runtime.h>
#include <stdint.h>

typedef __bf16 bf16x8 __attribute__((ext_vector_type(8)));
typedef float floatx4 __attribute__((ext_vector_type(4)));
typedef unsigned int u32x4 __attribute__((ext_vector_type(4)));
typedef unsigned long long u64x2 __attribute__((ext_vector_type(2)));

#define T_STEPS 512
#define BATCH   64
#define HDIM    512
#define NGATE   1024   // 2*H
#define IDIM    512
#define RBLOCKS 32     // recurrent blocks, 16 cols each

__device__ __forceinline__ unsigned short f2bf(float f) {
  unsigned int u = __builtin_bit_cast(unsigned int, f);
  u += 0x7fffu + ((u >> 16) & 1u);
  return (unsigned short)(u >> 16);
}
__device__ __forceinline__ float bf2f(unsigned short s) {
  unsigned int u = ((unsigned int)s) << 16;
  return __builtin_bit_cast(float, u);
}

// ---------------- fp32 -> bf16 hi + lo residual ----------------
__global__ void cvt_split_kernel(const float4* __restrict__ src,
                                 ushort4* __restrict__ hi, ushort4* __restrict__ lo, int n4) {
  int i = blockIdx.x * blockDim.x + threadIdx.x;
  if (i >= n4) return;
  float4 v = src[i];
  ushort4 h, l;
  h.x = f2bf(v.x); l.x = f2bf(v.x - bf2f(h.x));
  h.y = f2bf(v.y); l.y = f2bf(v.y - bf2f(h.y));
  h.z = f2bf(v.z); l.z = f2bf(v.z - bf2f(h.z));
  h.w = f2bf(v.w); l.w = f2bf(v.w - bf2f(h.w));
  hi[i] = h; lo[i] = l;
}

// biasc[i] = bih[i] + (i < H ? bhh[i] : 0)
__global__ void bias_kernel(const float* __restrict__ a, const float* __restrict__ b,
                            float* __restrict__ c, int n) {
  int i = blockIdx.x * blockDim.x + threadIdx.x;
  if (i < n) c[i] = a[i] + (i < HDIM ? b[i] : 0.0f);
}

// ---------------- async global->LDS 16B ----------------
__device__ __forceinline__ void g2l16(const void* g, void* l) {
  __builtin_amdgcn_global_load_lds(
      (const __attribute__((address_space(1))) unsigned int*)g,
      (__attribute__((address_space(3))) unsigned int*)l, 16, 0, 0);
}

// ---------------- Gi GEMM, split-split: C = (Ahi+Alo)(Bhi+Blo)^T + bias ----------------
__global__ __launch_bounds__(256) void gemm_bt(
    const unsigned short* __restrict__ Ahi,
    const unsigned short* __restrict__ Alo,
    const unsigned short* __restrict__ Bhi,
    const unsigned short* __restrict__ Blo,
    const float* __restrict__ bias,
    float* __restrict__ C,
    int M, int N, int K) {
  __shared__ unsigned short Ahs[128 * 32];
  __shared__ unsigned short Als[128 * 32];
  __shared__ unsigned short Bhs[128 * 32];
  __shared__ unsigned short Bls[128 * 32];
  const int tid  = threadIdx.x;
  const int w    = tid >> 6, lane = tid & 63;
  const int m16  = lane & 15, quad = lane >> 4;
  const int gn   = N >> 7;
  const int by   = blockIdx.x / gn, bx = blockIdx.x % gn;
  const int wm   = w & 1, wn = w >> 1;

  const int rr = lane >> 2;
  const int cc = lane & 3;
  const size_t ro0 = (size_t)((w*2+0)*16 + rr) * K + cc*8;
  const size_t ro1 = (size_t)((w*2+1)*16 + rr) * K + cc*8;
  const unsigned short* Ah0 = Ahi + (size_t)by*128*K + ro0;
  const unsigned short* Ah1 = Ahi + (size_t)by*128*K + ro1;
  const unsigned short* Al0 = Alo + (size_t)by*128*K + ro0;
  const unsigned short* Al1 = Alo + (size_t)by*128*K + ro1;
  const unsigned short* Bh0 = Bhi + (size_t)bx*128*K + ro0;
  const unsigned short* Bh1 = Bhi + (size_t)bx*128*K + ro1;
  const unsigned short* Bl0 = Blo + (size_t)bx*128*K + ro0;
  const unsigned short* Bl1 = Blo + (size_t)bx*128*K + ro1;

  floatx4 acc[4][4] = {};

  for (int k0 = 0; k0 < K; k0 += 32) {
    g2l16(Ah0 + k0, &Ahs[(w*2+0)*512]);
    g2l16(Ah1 + k0, &Ahs[(w*2+1)*512]);
    g2l16(Al0 + k0, &Als[(w*2+0)*512]);
    g2l16(Al1 + k0, &Als[(w*2+1)*512]);
    g2l16(Bh0 + k0, &Bhs[(w*2+0)*512]);
    g2l16(Bh1 + k0, &Bhs[(w*2+1)*512]);
    g2l16(Bl0 + k0, &Bls[(w*2+0)*512]);
    g2l16(Bl1 + k0, &Bls[(w*2+1)*512]);
    __syncthreads();

    bf16x8 ah[4], al[4], bh[4], bl[4];
#pragma unroll
    for (int mt = 0; mt < 4; ++mt) {
      ah[mt] = *(const bf16x8*)&Ahs[(wm*64 + mt*16 + m16)*32 + quad*8];
      al[mt] = *(const bf16x8*)&Als[(wm*64 + mt*16 + m16)*32 + quad*8];
    }
#pragma unroll
    for (int nt = 0; nt < 4; ++nt) {
      bh[nt] = *(const bf16x8*)&Bhs[(wn*64 + nt*16 + m16)*32 + quad*8];
      bl[nt] = *(const bf16x8*)&Bls[(wn*64 + nt*16 + m16)*32 + quad*8];
    }
#pragma unroll
    for (int mt = 0; mt < 4; ++mt)
#pragma unroll
      for (int nt = 0; nt < 4; ++nt) {
        acc[mt][nt] = __builtin_amdgcn_mfma_f32_16x16x32_bf16(ah[mt], bh[nt], acc[mt][nt], 0, 0, 0);
        acc[mt][nt] = __builtin_amdgcn_mfma_f32_16x16x32_bf16(al[mt], bh[nt], acc[mt][nt], 0, 0, 0);
        acc[mt][nt] = __builtin_amdgcn_mfma_f32_16x16x32_bf16(ah[mt], bl[nt], acc[mt][nt], 0, 0, 0);
      }
    __syncthreads();
  }

#pragma unroll
  for (int nt = 0; nt < 4; ++nt) {
    int col = bx*128 + wn*64 + nt*16 + m16;
    float bv = bias[col];
#pragma unroll
    for (int mt = 0; mt < 4; ++mt) {
      int row0 = by*128 + wm*64 + mt*16 + quad*4;
#pragma unroll
      for (int r = 0; r < 4; ++r)
        C[(size_t)(row0 + r)*N + col] = acc[mt][nt][r] + bv;
    }
  }
}

// ---- persistent recurrent kernel: R2 wave-cohort protocol + LDS weights + no-drain hint flag ----
// h element = u32: (bf16_hi << 16) | (bf16_lo & ~3) | (t & 3). Double buffer by t&1.
// Wave-cohort: wave w of block b depends only on wave w of every block (batch rows are
// independent). Per-wave flags; zero __syncthreads in the t-loop.
// Producer: phase-stamped h stores (agent atomics) -> HINT flag immediately (NO vmcnt
// drain: saves 1 MALL RTT/step). Consumer: poll 4B hint, bulk-load payload (R2 pipelining),
// then verify the 2-bit phase PER KK (only 4 u64 live per check - avoids R4's 128-reg
// verify that destroyed the load pipeline); rare straggler reload with backoff + cap
// (cap -> wrong results -> fast bench failure, never a hang).
// Overwrite safety (skew<=1, same as R2): a wave publishes flag t+1 only after computing
// h_t, which data-depends on its fully-verified h_{t-1} loads; a producer enters t+1 only
// after cohort flags >= t+1. Phase ABA distance is 2 mod 4 -> always detectable.
// Weights live in LDS (64 KB/block, shared by 4 waves): no compiler-issued global weight
// reloads competing with the latency-critical payload loads (R2 at 172 VGPR was reloading
// all 256 weight VGPRs from global every step).
__global__ __launch_bounds__(256, 1) void mgu_recur(
    const float* __restrict__ Gi,            // [T*B, 1024] fp32 (f: both biases; n: b_ih only)
    const unsigned short* __restrict__ Whi,  // [1024, 512] bf16 hi
    const unsigned short* __restrict__ Wlo,  // [1024, 512] bf16 lo
    const float* __restrict__ bhh,           // [1024] fp32 (n-half used)
    unsigned int* __restrict__ hbuf,         // [2][64][512] u32 packed (memset 0x03 = phase 3)
    unsigned int* __restrict__ flags,        // 128 words, stride 32 (zeroed)
    float* __restrict__ out) {               // [T*B, 512] fp32
  const int tid  = threadIdx.x;
  const int w    = tid >> 6, lane = tid & 63;
  const int m16  = lane & 15, quad = lane >> 4;
  const int j0   = blockIdx.x * 16;

  const float bnb = bhh[512 + j0 + m16];   // b_hh_n for this lane's output column

  // ---- weights -> LDS (one copy per block; same fragment layout for all 4 waves) ----
  __shared__ bf16x8 wlds[4][16][64];       // [fh,nh,fl,nl][kk][lane]
#pragma unroll
  for (int q = 0; q < 4; ++q) {
    int kk = w*4 + q;
    size_t of = (size_t)(j0 + m16)       * 512 + kk*32 + quad*8;
    size_t on = (size_t)(512 + j0 + m16) * 512 + kk*32 + quad*8;
    wlds[0][kk][lane] = *(const bf16x8*)&Whi[of];
    wlds[1][kk][lane] = *(const bf16x8*)&Whi[on];
    wlds[2][kk][lane] = *(const bf16x8*)&Wlo[of];
    wlds[3][kk][lane] = *(const bf16x8*)&Wlo[on];
  }
  __syncthreads();

  const int arow = w*16 + m16;   // batch row this lane reads for the A fragment

  unsigned int* myflag = flags + (blockIdx.x*4 + w) * 32;
  const unsigned int* pollflag = flags + ((lane & 31)*4 + w) * 32;  // cohort w, block lane&31

#pragma unroll 1
  for (int t = 0; t < T_STEPS; ++t) {
    // Gi prefetch (fp32, h-independent) — overlaps the flag poll
    float gif[4], gin[4];
#pragma unroll
    for (int r = 0; r < 4; ++r) {
      size_t row = (size_t)t*64 + w*16 + quad*4 + r;
      gif[r] = Gi[row*1024 + j0 + m16];
      gin[r] = Gi[row*1024 + 512 + j0 + m16];
    }

    floatx4 accf0 = {}, accf1 = {}, accf2 = {};
    floatx4 accn0 = {}, accn1 = {}, accn2 = {};

    if (t > 0) {
      // cohort HINT poll: 1 word/lane, tight (uncapped, as proven in R2)
      unsigned int fv;
      do {
        fv = __hip_atomic_load(pollflag, __ATOMIC_RELAXED, __HIP_MEMORY_SCOPE_AGENT);
      } while (__any((int)(fv < (unsigned int)t)));

      const unsigned int ph = (unsigned int)((t-1) & 3);
      const unsigned long long* hrow =
          (const unsigned long long*)(hbuf + (size_t)((t-1)&1)*BATCH*HDIM)
          + (size_t)arow*256 + quad*4;   // row stride 256 u64; col base quad*8 elems

      // bulk payload load (R2 pipelining: all 64 u64 in flight)
      unsigned long long pk[16][4];
#pragma unroll
      for (int kk = 0; kk < 16; ++kk)
#pragma unroll
        for (int i = 0; i < 4; ++i)
          pk[kk][i] = __hip_atomic_load(hrow + kk*16 + i,
                        __ATOMIC_RELAXED, __HIP_MEMORY_SCOPE_AGENT);

      // per-kk: verify 4 u64 phases (8 fields), rare reload; unpack; 6 MFMA
#pragma unroll
      for (int kk = 0; kk < 16; ++kk) {
        {
          int sp = 0;
          for (;;) {
            unsigned int bad =
                (((unsigned int)pk[kk][0] ^ ph) | ((unsigned int)(pk[kk][0] >> 32) ^ ph) |
                 ((unsigned int)pk[kk][1] ^ ph) | ((unsigned int)(pk[kk][1] >> 32) ^ ph) |
                 ((unsigned int)pk[kk][2] ^ ph) | ((unsigned int)(pk[kk][2] >> 32) ^ ph) |
                 ((unsigned int)pk[kk][3] ^ ph) | ((unsigned int)(pk[kk][3] >> 32) ^ ph)) & 3u;
            if (!__any((int)bad)) break;
            if (++sp >= (1 << 15)) break;   // cap: wrong results, not a hang
            __builtin_amdgcn_s_sleep(1);
#pragma unroll
            for (int i = 0; i < 4; ++i)
              pk[kk][i] = __hip_atomic_load(hrow + kk*16 + i,
                            __ATOMIC_RELAXED, __HIP_MEMORY_SCOPE_AGENT);
          }
        }
        unsigned int e0 = (unsigned int)pk[kk][0], e1 = (unsigned int)(pk[kk][0] >> 32);
        unsigned int e2 = (unsigned int)pk[kk][1], e3 = (unsigned int)(pk[kk][1] >> 32);
        unsigned int e4 = (unsigned int)pk[kk][2], e5 = (unsigned int)(pk[kk][2] >> 32);
        unsigned int e6 = (unsigned int)pk[kk][3], e7 = (unsigned int)(pk[kk][3] >> 32);
        u32x4 h4 = { __builtin_amdgcn_perm(e1, e0, 0x07060302u),
                     __builtin_amdgcn_perm(e3, e2, 0x07060302u),
                     __builtin_amdgcn_perm(e5, e4, 0x07060302u),
                     __builtin_amdgcn_perm(e7, e6, 0x07060302u) };
        u32x4 l4 = { __builtin_amdgcn_perm(e1, e0, 0x05040100u) & 0xFFFCFFFCu,
                     __builtin_amdgcn_perm(e3, e2, 0x05040100u) & 0xFFFCFFFCu,
                     __builtin_amdgcn_perm(e5, e4, 0x05040100u) & 0xFFFCFFFCu,
                     __builtin_amdgcn_perm(e7, e6, 0x05040100u) & 0xFFFCFFFCu };
        bf16x8 ah = __builtin_bit_cast(bf16x8, h4);
        bf16x8 al = __builtin_bit_cast(bf16x8, l4);
        bf16x8 fh = wlds[0][kk][lane], nh = wlds[1][kk][lane];
        bf16x8 fl = wlds[2][kk][lane], nl = wlds[3][kk][lane];
        accf0 = __builtin_amdgcn_mfma_f32_16x16x32_bf16(ah, fh, accf0, 0, 0, 0);
        accf1 = __builtin_amdgcn_mfma_f32_16x16x32_bf16(al, fh, accf1, 0, 0, 0);
        accf2 = __builtin_amdgcn_mfma_f32_16x16x32_bf16(ah, fl, accf2, 0, 0, 0);
        accn0 = __builtin_amdgcn_mfma_f32_16x16x32_bf16(ah, nh, accn0, 0, 0, 0);
        accn1 = __builtin_amdgcn_mfma_f32_16x16x32_bf16(al, nh, accn1, 0, 0, 0);
        accn2 = __builtin_amdgcn_mfma_f32_16x16x32_bf16(ah, nl, accn2, 0, 0, 0);
      }
    }

    // gates + nonlinearity (fp32); phase-stamped h stores, then HINT flag (no drain)
    const unsigned int phw = (unsigned int)(t & 3);
    unsigned int* hcur = hbuf + (size_t)(t&1)*BATCH*HDIM;
    float hv[4];
#pragma unroll
    for (int r = 0; r < 4; ++r) {
      float xf = gif[r] + (accf0[r] + accf1[r] + accf2[r]);
      float f  = 1.0f / (1.0f + __expf(-xf));
      float xn = gin[r] + f * (accn0[r] + accn1[r] + accn2[r] + bnb);
      float ex = __expf(-2.0f * xn);
      float h  = (1.0f - ex) / (1.0f + ex);    // tanh
      hv[r] = h;
      unsigned short hh = f2bf(h);
      unsigned short hl = f2bf(h - bf2f(hh));
      unsigned int packed = ((unsigned int)hh << 16) | ((unsigned int)hl & 0xFFFCu) | phw;
      int row = w*16 + quad*4 + r;
      __hip_atomic_store(hcur + (size_t)row*512 + j0 + m16, packed,
                         __ATOMIC_RELAXED, __HIP_MEMORY_SCOPE_AGENT);
    }

    // HINT flag: issued right after the h stores, NO vmcnt drain (phase bits carry validity)
    if (lane == 0)
      __hip_atomic_store(myflag, (unsigned int)(t + 1),
                         __ATOMIC_RELAXED, __HIP_MEMORY_SCOPE_AGENT);

    // out store AFTER flag: off the inter-wave critical path
#pragma unroll
    for (int r = 0; r < 4; ++r) {
      int row = w*16 + quad*4 + r;
      __builtin_nontemporal_store(hv[r], &out[((size_t)t*64 + row)*512 + j0 + m16]);
    }
  }
}

// ---------------- launch ----------------
extern "C" void kernel_launch(void* const* d_in, const int* in_sizes, int n_in,
                              void* d_out, int out_size, void* d_ws, size_t ws_size,
                              hipStream_t stream) {
  (void)in_sizes; (void)n_in; (void)out_size; (void)ws_size;
  const float* X   = (const float*)d_in[0];   // [512,64,512]
  const float* Wih = (const float*)d_in[1];   // [1024,512]
  const float* Whh = (const float*)d_in[2];   // [1024,512]
  const float* bih = (const float*)d_in[3];   // [1024]
  const float* bhh = (const float*)d_in[4];   // [1024]
  float* out = (float*)d_out;

  const int TB = T_STEPS * BATCH;  // 32768

  // workspace layout (~207 MB)
  unsigned short* Xhi    = (unsigned short*)d_ws;                    // TB*IDIM bf16
  unsigned short* Xlo    = Xhi   + (size_t)TB * IDIM;
  unsigned short* WihHi  = Xlo   + (size_t)TB * IDIM;                // NGATE*IDIM
  unsigned short* WihLo  = WihHi + (size_t)NGATE * IDIM;
  unsigned short* WhhHi  = WihLo + (size_t)NGATE * IDIM;             // NGATE*HDIM
  unsigned short* WhhLo  = WhhHi + (size_t)NGATE * HDIM;
  float*          biasc  = (float*)(WhhLo + (size_t)NGATE * HDIM);   // NGATE
  float*          Gi     = biasc + NGATE;                            // TB*NGATE fp32
  unsigned int*   hbuf   = (unsigned int*)(Gi + (size_t)TB * NGATE); // [2][64][512] u32
  unsigned int*   flags  = hbuf + (size_t)2 * BATCH * HDIM;          // 128 x stride-32 u32

  // hbuf -> phase 3 (0x03030303): never a valid expected phase (t=1 expects 0, t=2 expects 1)
  (void)hipMemsetAsync(hbuf, 0x03, (size_t)2 * BATCH * HDIM * sizeof(unsigned int), stream);
  (void)hipMemsetAsync(flags, 0, (size_t)RBLOCKS * 4 * 32 * sizeof(unsigned int), stream);

  int n4;
  n4 = TB * IDIM / 4;
  cvt_split_kernel<<<n4/256, 256, 0, stream>>>((const float4*)X, (ushort4*)Xhi, (ushort4*)Xlo, n4);
  n4 = NGATE * IDIM / 4;
  cvt_split_kernel<<<n4/256, 256, 0, stream>>>((const float4*)Wih, (ushort4*)WihHi, (ushort4*)WihLo, n4);
  n4 = NGATE * HDIM / 4;
  cvt_split_kernel<<<n4/256, 256, 0, stream>>>((const float4*)Whh, (ushort4*)WhhHi, (ushort4*)WhhLo, n4);
  bias_kernel<<<4, 256, 0, stream>>>(bih, bhh, biasc, NGATE);

  gemm_bt<<<(TB/128)*(NGATE/128), 256, 0, stream>>>(Xhi, Xlo, WihHi, WihLo, biasc, Gi, TB, NGATE, IDIM);

  mgu_recur<<<RBLOCKS, 256, 0, stream>>>(Gi, WhhHi, WhhLo, bhh, hbuf, flags, out);
}